// Round 1
// baseline (2044.924 us; speedup 1.0000x reference)
//
#include <hip/hip_runtime.h>
#include <hip/hip_bf16.h>

// Problem constants
#define BB 2
#define TT 2048
#define CC 768
#define HH 8
#define DD 96
#define N3 2304   // 3*C
#define BH (BB*HH)

#define TILE 64
#define BK 16

// ---------------------------------------------------------------------------
// Kernel 1: QKV GEMM  x[4096,768] @ W_attn[768,2304] + b_attn
// Epilogue scatters into Q [B,H,T,D] (pre-scaled), Kt [B,H,D,T], V [B,H,T,D]
// ---------------------------------------------------------------------------
__global__ __launch_bounds__(256) void qkv_gemm_kernel(
    const float* __restrict__ A, const float* __restrict__ Bw,
    const float* __restrict__ bias,
    float* __restrict__ Q, float* __restrict__ Kt, float* __restrict__ V)
{
    __shared__ float As[BK][TILE];   // transposed: As[k][m]
    __shared__ float Bs[BK][TILE];   // Bs[k][n]

    const int tid = threadIdx.x;
    const int tx = tid & 15;         // 0..15 (n micro)
    const int ty = tid >> 4;         // 0..15 (m micro)
    const int m0 = blockIdx.y * TILE;
    const int n0 = blockIdx.x * TILE;

    // load-index decomposition
    const int lr  = tid >> 2;        // 0..63  A row within tile
    const int lc4 = tid & 3;         // 0..3   A float4 col within 16
    const int br  = tid >> 4;        // 0..15  B row within BK
    const int bc4 = tid & 15;        // 0..15  B float4 col within 64

    float acc[4][4] = {};

    for (int k0 = 0; k0 < CC; k0 += BK) {
        float4 av = *(const float4*)&A[(m0 + lr) * CC + k0 + lc4 * 4];
        float4 bv = *(const float4*)&Bw[(k0 + br) * N3 + n0 + bc4 * 4];
        __syncthreads();   // previous iteration's LDS reads done
        As[lc4*4+0][lr] = av.x;
        As[lc4*4+1][lr] = av.y;
        As[lc4*4+2][lr] = av.z;
        As[lc4*4+3][lr] = av.w;
        *(float4*)&Bs[br][bc4*4] = bv;
        __syncthreads();
        #pragma unroll
        for (int kk = 0; kk < BK; ++kk) {
            float4 a4 = *(const float4*)&As[kk][ty*4];
            float4 b4 = *(const float4*)&Bs[kk][tx*4];
            float a[4] = {a4.x, a4.y, a4.z, a4.w};
            float b[4] = {b4.x, b4.y, b4.z, b4.w};
            #pragma unroll
            for (int i = 0; i < 4; ++i)
                #pragma unroll
                for (int j = 0; j < 4; ++j)
                    acc[i][j] += a[i] * b[j];
        }
    }

    const float scale = 0.10206207261596575f;  // 1/sqrt(96)
    #pragma unroll
    for (int i = 0; i < 4; ++i) {
        const int m = m0 + ty*4 + i;
        const int b = m >> 11;           // / 2048
        const int t = m & 2047;
        #pragma unroll
        for (int j = 0; j < 4; ++j) {
            const int n = n0 + tx*4 + j;
            float v = acc[i][j] + bias[n];
            const int part = n / CC;
            const int c = n % CC;
            const int h = c / DD;
            const int d = c % DD;
            const int bh = b * HH + h;
            if (part == 0)      Q[(bh*TT + t)*DD + d] = v * scale;
            else if (part == 1) Kt[(bh*DD + d)*TT + t] = v;
            else                V[(bh*TT + t)*DD + d] = v;
        }
    }
}

// ---------------------------------------------------------------------------
// Kernel 2: causal attention, one block per (b,h,q-row).
// Scores for all keys fit in LDS (2048 floats = 8KB).
// ---------------------------------------------------------------------------
__global__ __launch_bounds__(256) void attn_kernel(
    const float* __restrict__ Q, const float* __restrict__ Kt,
    const float* __restrict__ V, float* __restrict__ Y)
{
    const int qrow = blockIdx.x;
    const int bh   = blockIdx.y;
    const int tid  = threadIdx.x;
    const int nk   = qrow + 1;

    __shared__ float qs[DD];
    __shared__ float sc[TT];
    __shared__ float red[4];
    __shared__ float part[2*DD];

    const float* Qp = Q  + (bh*TT + qrow)*DD;
    const float* Kp = Kt + bh*DD*TT;
    const float* Vp = V  + bh*TT*DD;

    if (tid < DD) qs[tid] = Qp[tid];
    __syncthreads();

    // ---- scores (float4 over keys; Kt layout makes loads coalesced) ----
    float lmax = -1e30f;
    for (int k = tid*4; k < nk; k += 1024) {
        float4 a = {0.f, 0.f, 0.f, 0.f};
        #pragma unroll 8
        for (int d = 0; d < DD; ++d) {
            const float qd = qs[d];
            const float4 kv = *(const float4*)&Kp[d*TT + k];
            a.x += qd*kv.x; a.y += qd*kv.y; a.z += qd*kv.z; a.w += qd*kv.w;
        }
        const int rem = nk - k;
        sc[k] = a.x; lmax = fmaxf(lmax, a.x);
        if (rem > 1) { sc[k+1] = a.y; lmax = fmaxf(lmax, a.y); }
        if (rem > 2) { sc[k+2] = a.z; lmax = fmaxf(lmax, a.z); }
        if (rem > 3) { sc[k+3] = a.w; lmax = fmaxf(lmax, a.w); }
    }

    // ---- block max ----
    #pragma unroll
    for (int off = 32; off > 0; off >>= 1)
        lmax = fmaxf(lmax, __shfl_down(lmax, off, 64));
    const int wave = tid >> 6;
    if ((tid & 63) == 0) red[wave] = lmax;
    __syncthreads();
    const float m = fmaxf(fmaxf(red[0], red[1]), fmaxf(red[2], red[3]));
    __syncthreads();   // done reading red (max) before reuse for sums

    // ---- exp + block sum ----
    float lsum = 0.f;
    for (int k = tid*4; k < nk; k += 1024) {
        const int rem = nk - k;
        float p;
        p = __expf(sc[k] - m); sc[k] = p; lsum += p;
        if (rem > 1) { p = __expf(sc[k+1] - m); sc[k+1] = p; lsum += p; }
        if (rem > 2) { p = __expf(sc[k+2] - m); sc[k+2] = p; lsum += p; }
        if (rem > 3) { p = __expf(sc[k+3] - m); sc[k+3] = p; lsum += p; }
    }
    #pragma unroll
    for (int off = 32; off > 0; off >>= 1)
        lsum += __shfl_down(lsum, off, 64);
    if ((tid & 63) == 0) red[wave] = lsum;
    __syncthreads();   // sums visible AND exp'd sc visible
    const float inv_l = 1.0f / (red[0] + red[1] + red[2] + red[3]);

    // ---- P @ V : 2 groups x 96 dims, coalesced V reads ----
    const int g = tid / DD;     // 0,1 active; 2 idle
    const int d = tid % DD;
    if (g < 2) {
        float acc = 0.f;
        for (int k = g; k < nk; k += 2)
            acc += sc[k] * Vp[k*DD + d];
        part[g*DD + d] = acc;
    }
    __syncthreads();
    if (tid < DD) {
        const float y = (part[tid] + part[DD + tid]) * inv_l;
        const int b = bh >> 3;
        const int h = bh & 7;
        Y[(b*TT + qrow)*CC + h*DD + tid] = y;
    }
}

// ---------------------------------------------------------------------------
// Kernel 3: out = Y[4096,768] @ W_proj[768,768] + b_proj
// ---------------------------------------------------------------------------
__global__ __launch_bounds__(256) void proj_gemm_kernel(
    const float* __restrict__ A, const float* __restrict__ Bw,
    const float* __restrict__ bias, float* __restrict__ out)
{
    __shared__ float As[BK][TILE];
    __shared__ float Bs[BK][TILE];

    const int tid = threadIdx.x;
    const int tx = tid & 15;
    const int ty = tid >> 4;
    const int m0 = blockIdx.y * TILE;
    const int n0 = blockIdx.x * TILE;

    const int lr  = tid >> 2;
    const int lc4 = tid & 3;
    const int br  = tid >> 4;
    const int bc4 = tid & 15;

    float acc[4][4] = {};

    for (int k0 = 0; k0 < CC; k0 += BK) {
        float4 av = *(const float4*)&A[(m0 + lr) * CC + k0 + lc4 * 4];
        float4 bv = *(const float4*)&Bw[(k0 + br) * CC + n0 + bc4 * 4];
        __syncthreads();
        As[lc4*4+0][lr] = av.x;
        As[lc4*4+1][lr] = av.y;
        As[lc4*4+2][lr] = av.z;
        As[lc4*4+3][lr] = av.w;
        *(float4*)&Bs[br][bc4*4] = bv;
        __syncthreads();
        #pragma unroll
        for (int kk = 0; kk < BK; ++kk) {
            float4 a4 = *(const float4*)&As[kk][ty*4];
            float4 b4 = *(const float4*)&Bs[kk][tx*4];
            float a[4] = {a4.x, a4.y, a4.z, a4.w};
            float b[4] = {b4.x, b4.y, b4.z, b4.w};
            #pragma unroll
            for (int i = 0; i < 4; ++i)
                #pragma unroll
                for (int j = 0; j < 4; ++j)
                    acc[i][j] += a[i] * b[j];
        }
    }

    #pragma unroll
    for (int i = 0; i < 4; ++i) {
        const int m = m0 + ty*4 + i;
        #pragma unroll
        for (int j = 0; j < 4; ++j) {
            const int n = n0 + tx*4 + j;
            out[m*CC + n] = acc[i][j] + bias[n];
        }
    }
}

extern "C" void kernel_launch(void* const* d_in, const int* in_sizes, int n_in,
                              void* d_out, int out_size, void* d_ws, size_t ws_size,
                              hipStream_t stream) {
    const float* x      = (const float*)d_in[0];   // [2,2048,768]
    const float* W_attn = (const float*)d_in[1];   // [768,2304]
    const float* b_attn = (const float*)d_in[2];   // [2304]
    const float* W_proj = (const float*)d_in[3];   // [768,768]
    const float* b_proj = (const float*)d_in[4];   // [768]
    float* out = (float*)d_out;                    // [2,2048,768]

    const size_t SLICE = (size_t)BH * TT * DD;     // 3,145,728 floats
    float* ws = (float*)d_ws;
    float* Q  = ws;                // [B,H,T,D] pre-scaled by 1/sqrt(D)
    float* Kt = Q  + SLICE;        // [B,H,D,T]
    float* V  = Kt + SLICE;        // [B,H,T,D]
    float* Y  = V  + SLICE;        // [B,T,C]

    qkv_gemm_kernel<<<dim3(N3/TILE, (BB*TT)/TILE), 256, 0, stream>>>(
        x, W_attn, b_attn, Q, Kt, V);
    attn_kernel<<<dim3(TT, BH), 256, 0, stream>>>(Q, Kt, V, Y);
    proj_gemm_kernel<<<dim3(CC/TILE, (BB*TT)/TILE), 256, 0, stream>>>(
        Y, W_proj, b_proj, out);
}

// Round 2
// 427.999 us; speedup vs baseline: 4.7779x; 4.7779x over previous
//
#include <hip/hip_runtime.h>
#include <hip/hip_bf16.h>

// Problem constants
#define BB 2
#define TT 2048
#define CC 768
#define HH 8
#define DD 96
#define N3 2304   // 3*C
#define BH (BB*HH)

#define TILE 64
#define BK 16

typedef __bf16 bf16x8 __attribute__((ext_vector_type(8)));
typedef float f32x4 __attribute__((ext_vector_type(4)));

__device__ __forceinline__ ushort f2bf(float f) {
    unsigned u = __builtin_bit_cast(unsigned, f);
    u += 0x7fffu + ((u >> 16) & 1u);   // round-to-nearest-even (no NaN inputs here)
    return (ushort)(u >> 16);
}

// ---------------------------------------------------------------------------
// Kernel 1: QKV GEMM  x[4096,768] @ W_attn[768,2304] + b_attn
// Epilogue -> bf16: Q [BH,T,96] (pre-scaled 1/sqrt(96)), K [BH,T,96],
//                   Vt [BH,96,T] (transposed for MFMA B-fragment reads)
// ---------------------------------------------------------------------------
__global__ __launch_bounds__(256) void qkv_gemm_kernel(
    const float* __restrict__ A, const float* __restrict__ Bw,
    const float* __restrict__ bias,
    ushort* __restrict__ Qb, ushort* __restrict__ Kb, ushort* __restrict__ Vt)
{
    __shared__ float As[BK][TILE];   // As[k][m]
    __shared__ float Bs[BK][TILE];   // Bs[k][n]

    const int tid = threadIdx.x;
    const int tx = tid & 15;
    const int ty = tid >> 4;
    const int m0 = blockIdx.y * TILE;
    const int n0 = blockIdx.x * TILE;

    const int lr  = tid >> 2;
    const int lc4 = tid & 3;
    const int br  = tid >> 4;
    const int bc4 = tid & 15;

    float acc[4][4] = {};

    for (int k0 = 0; k0 < CC; k0 += BK) {
        float4 av = *(const float4*)&A[(m0 + lr) * CC + k0 + lc4 * 4];
        float4 bv = *(const float4*)&Bw[(k0 + br) * N3 + n0 + bc4 * 4];
        __syncthreads();
        As[lc4*4+0][lr] = av.x;
        As[lc4*4+1][lr] = av.y;
        As[lc4*4+2][lr] = av.z;
        As[lc4*4+3][lr] = av.w;
        *(float4*)&Bs[br][bc4*4] = bv;
        __syncthreads();
        #pragma unroll
        for (int kk = 0; kk < BK; ++kk) {
            float4 a4 = *(const float4*)&As[kk][ty*4];
            float4 b4 = *(const float4*)&Bs[kk][tx*4];
            float a[4] = {a4.x, a4.y, a4.z, a4.w};
            float b[4] = {b4.x, b4.y, b4.z, b4.w};
            #pragma unroll
            for (int i = 0; i < 4; ++i)
                #pragma unroll
                for (int j = 0; j < 4; ++j)
                    acc[i][j] += a[i] * b[j];
        }
    }

    const float scale = 0.10206207261596575f;  // 1/sqrt(96)
    #pragma unroll
    for (int i = 0; i < 4; ++i) {
        const int m = m0 + ty*4 + i;
        const int b = m >> 11;           // / 2048
        const int t = m & 2047;
        #pragma unroll
        for (int j = 0; j < 4; ++j) {
            const int n = n0 + tx*4 + j;
            float v = acc[i][j] + bias[n];
            const int part = n / CC;
            const int c = n % CC;
            const int h = c / DD;
            const int d = c % DD;
            const int bh = b * HH + h;
            if (part == 0)      Qb[((size_t)bh*TT + t)*DD + d] = f2bf(v * scale);
            else if (part == 1) Kb[((size_t)bh*TT + t)*DD + d] = f2bf(v);
            else                Vt[((size_t)bh*DD + d)*TT + t] = f2bf(v);
        }
    }
}

// ---------------------------------------------------------------------------
// Kernel 2: flash-style causal attention with bf16 MFMA.
// Block = 64 q-rows (4 waves x 16), iterate 64-key tiles.
// Layouts (HW-verified, 16x16x32_bf16):
//   A[m=lane&15][k=quad*8+j], B[k=quad*8+j][n=lane&15],
//   C/D[row=quad*4+reg][col=lane&15]
// ---------------------------------------------------------------------------
__global__ __launch_bounds__(256) void attn_mfma_kernel(
    const ushort* __restrict__ Qb, const ushort* __restrict__ Kb,
    const ushort* __restrict__ Vt, float* __restrict__ Y)
{
    __shared__ __align__(16) ushort Kl[64][104];     // [key][d], +8 pad
    __shared__ __align__(16) ushort Vl[96][72];      // [d][key], +8 pad
    __shared__ __align__(16) ushort Pl[4][16][72];   // per-wave P round-trip

    const int tid  = threadIdx.x;
    const int w    = tid >> 6;       // wave 0..3
    const int lane = tid & 63;
    const int quad = lane >> 4;      // 0..3
    const int col  = lane & 15;      // 0..15
    const int qb   = blockIdx.x;     // 0..31
    const int bh   = blockIdx.y;     // 0..15
    const int q0   = qb * 64;

    // Q fragments (A-layout): m = col, k = ks*32 + quad*8 + j, contiguous 16B
    const int qrow = q0 + w*16 + col;
    const ushort* Qp = Qb + ((size_t)bh*TT + qrow)*DD;
    bf16x8 qf[3];
    #pragma unroll
    for (int ks = 0; ks < 3; ++ks)
        qf[ks] = *(const bf16x8*)(Qp + ks*32 + quad*8);

    const ushort* Kg = Kb + (size_t)bh*TT*DD;
    const ushort* Vg = Vt + (size_t)bh*DD*TT;

    f32x4 O[6] = {};                  // O[d-tile][reg], rows quad*4+reg
    float mrow[4], lrow[4];
    #pragma unroll
    for (int r = 0; r < 4; ++r) { mrow[r] = -1e30f; lrow[r] = 0.f; }

    for (int kt = 0; kt <= qb; ++kt) {
        const int k0 = kt * 64;
        __syncthreads();              // previous tile's LDS reads complete
        // stage K tile: 64 x 96 bf16, 768 16B-chunks, 3 per thread
        #pragma unroll
        for (int i = 0; i < 3; ++i) {
            int l = tid + i*256;
            int row = l / 12, ch = l % 12;
            uint4 vv = *(const uint4*)(Kg + (size_t)(k0 + row)*DD + ch*8);
            *(uint4*)&Kl[row][ch*8] = vv;
        }
        // stage V tile (transposed source): 96 x 64 bf16, 768 chunks
        #pragma unroll
        for (int i = 0; i < 3; ++i) {
            int l = tid + i*256;
            int row = l / 8, ch = l % 8;
            uint4 vv = *(const uint4*)(Vg + (size_t)row*TT + k0 + ch*8);
            *(uint4*)&Vl[row][ch*8] = vv;
        }
        __syncthreads();

        // ---- S = Q @ K^T : 4 col-tiles x 3 k-steps ----
        f32x4 s[4];
        #pragma unroll
        for (int c = 0; c < 4; ++c) {
            f32x4 acc = {0.f, 0.f, 0.f, 0.f};
            #pragma unroll
            for (int ks = 0; ks < 3; ++ks) {
                bf16x8 bf = *(const bf16x8*)&Kl[c*16 + col][ks*32 + quad*8];
                acc = __builtin_amdgcn_mfma_f32_16x16x32_bf16(qf[ks], bf, acc, 0, 0, 0);
            }
            s[c] = acc;
        }

        // ---- causal mask (diagonal tile only) ----
        if (kt == qb) {
            #pragma unroll
            for (int c = 0; c < 4; ++c)
                #pragma unroll
                for (int r = 0; r < 4; ++r) {
                    const int qlb = w*16 + quad*4 + r;   // q within block
                    const int klb = c*16 + col;          // key within tile
                    if (klb > qlb) s[c][r] = -1e30f;
                }
        }

        // ---- online softmax per row (row stats shared across quad lanes) ----
        float ps[4][4];
        #pragma unroll
        for (int r = 0; r < 4; ++r) {
            float mx = fmaxf(fmaxf(s[0][r], s[1][r]), fmaxf(s[2][r], s[3][r]));
            mx = fmaxf(mx, __shfl_xor(mx, 1, 64));
            mx = fmaxf(mx, __shfl_xor(mx, 2, 64));
            mx = fmaxf(mx, __shfl_xor(mx, 4, 64));
            mx = fmaxf(mx, __shfl_xor(mx, 8, 64));
            const float mnew  = fmaxf(mrow[r], mx);
            const float alpha = __expf(mrow[r] - mnew);
            mrow[r] = mnew;
            float rs = 0.f;
            #pragma unroll
            for (int c = 0; c < 4; ++c) {
                const float p = __expf(s[c][r] - mnew);
                ps[c][r] = p;
                rs += p;
            }
            rs += __shfl_xor(rs, 1, 64);
            rs += __shfl_xor(rs, 2, 64);
            rs += __shfl_xor(rs, 4, 64);
            rs += __shfl_xor(rs, 8, 64);
            lrow[r] = lrow[r]*alpha + rs;
            #pragma unroll
            for (int c2 = 0; c2 < 6; ++c2)
                O[c2][r] *= alpha;
        }

        // ---- P: C-layout -> LDS -> A-layout (wave-private, no barrier) ----
        #pragma unroll
        for (int c = 0; c < 4; ++c)
            #pragma unroll
            for (int r = 0; r < 4; ++r)
                Pl[w][quad*4 + r][c*16 + col] = f2bf(ps[c][r]);

        bf16x8 pf0 = *(const bf16x8*)&Pl[w][col][quad*8];        // k = 0..31
        bf16x8 pf1 = *(const bf16x8*)&Pl[w][col][32 + quad*8];   // k = 32..63

        // ---- O += P @ V : 6 d-tiles x 2 k-steps ----
        #pragma unroll
        for (int c2 = 0; c2 < 6; ++c2) {
            bf16x8 vb0 = *(const bf16x8*)&Vl[c2*16 + col][quad*8];
            bf16x8 vb1 = *(const bf16x8*)&Vl[c2*16 + col][32 + quad*8];
            O[c2] = __builtin_amdgcn_mfma_f32_16x16x32_bf16(pf0, vb0, O[c2], 0, 0, 0);
            O[c2] = __builtin_amdgcn_mfma_f32_16x16x32_bf16(pf1, vb1, O[c2], 0, 0, 0);
        }
    }

    // ---- epilogue: normalize, write Y [B,T,C] fp32 ----
    const int b = bh >> 3, h = bh & 7;
    #pragma unroll
    for (int r = 0; r < 4; ++r) {
        const int q = q0 + w*16 + quad*4 + r;
        const float inv = 1.0f / lrow[r];
        float* Yp = Y + ((size_t)b*TT + q)*CC + h*DD;
        #pragma unroll
        for (int c2 = 0; c2 < 6; ++c2)
            Yp[c2*16 + col] = O[c2][r] * inv;
    }
}

// ---------------------------------------------------------------------------
// Kernel 3: out = Y[4096,768] @ W_proj[768,768] + b_proj  (fp32)
// ---------------------------------------------------------------------------
__global__ __launch_bounds__(256) void proj_gemm_kernel(
    const float* __restrict__ A, const float* __restrict__ Bw,
    const float* __restrict__ bias, float* __restrict__ out)
{
    __shared__ float As[BK][TILE];
    __shared__ float Bs[BK][TILE];

    const int tid = threadIdx.x;
    const int tx = tid & 15;
    const int ty = tid >> 4;
    const int m0 = blockIdx.y * TILE;
    const int n0 = blockIdx.x * TILE;

    const int lr  = tid >> 2;
    const int lc4 = tid & 3;
    const int br  = tid >> 4;
    const int bc4 = tid & 15;

    float acc[4][4] = {};

    for (int k0 = 0; k0 < CC; k0 += BK) {
        float4 av = *(const float4*)&A[(m0 + lr) * CC + k0 + lc4 * 4];
        float4 bv = *(const float4*)&Bw[(k0 + br) * CC + n0 + bc4 * 4];
        __syncthreads();
        As[lc4*4+0][lr] = av.x;
        As[lc4*4+1][lr] = av.y;
        As[lc4*4+2][lr] = av.z;
        As[lc4*4+3][lr] = av.w;
        *(float4*)&Bs[br][bc4*4] = bv;
        __syncthreads();
        #pragma unroll
        for (int kk = 0; kk < BK; ++kk) {
            float4 a4 = *(const float4*)&As[kk][ty*4];
            float4 b4 = *(const float4*)&Bs[kk][tx*4];
            float a[4] = {a4.x, a4.y, a4.z, a4.w};
            float b[4] = {b4.x, b4.y, b4.z, b4.w};
            #pragma unroll
            for (int i = 0; i < 4; ++i)
                #pragma unroll
                for (int j = 0; j < 4; ++j)
                    acc[i][j] += a[i] * b[j];
        }
    }

    #pragma unroll
    for (int i = 0; i < 4; ++i) {
        const int m = m0 + ty*4 + i;
        #pragma unroll
        for (int j = 0; j < 4; ++j) {
            const int n = n0 + tx*4 + j;
            out[m*CC + n] = acc[i][j] + bias[n];
        }
    }
}

extern "C" void kernel_launch(void* const* d_in, const int* in_sizes, int n_in,
                              void* d_out, int out_size, void* d_ws, size_t ws_size,
                              hipStream_t stream) {
    const float* x      = (const float*)d_in[0];   // [2,2048,768]
    const float* W_attn = (const float*)d_in[1];   // [768,2304]
    const float* b_attn = (const float*)d_in[2];   // [2304]
    const float* W_proj = (const float*)d_in[3];   // [768,768]
    const float* b_proj = (const float*)d_in[4];   // [768]
    float* out = (float*)d_out;                    // [2,2048,768]

    const size_t SLICE = (size_t)BH * TT * DD;     // 3,145,728 elements
    ushort* Qb = (ushort*)d_ws;                    // bf16 [BH,T,96], pre-scaled
    ushort* Kb = Qb + SLICE;                       // bf16 [BH,T,96]
    ushort* Vt = Kb + SLICE;                       // bf16 [BH,96,T]
    float*  Y  = (float*)(Vt + SLICE);             // fp32 [B,T,C]

    qkv_gemm_kernel<<<dim3(N3/TILE, (BB*TT)/TILE), 256, 0, stream>>>(
        x, W_attn, b_attn, Qb, Kb, Vt);
    attn_mfma_kernel<<<dim3(TT/64, BH), 256, 0, stream>>>(Qb, Kb, Vt, Y);
    proj_gemm_kernel<<<dim3(CC/TILE, (BB*TT)/TILE), 256, 0, stream>>>(
        Y, W_proj, b_proj, out);
}

// Round 3
// 217.829 us; speedup vs baseline: 9.3878x; 1.9648x over previous
//
#include <hip/hip_runtime.h>
#include <hip/hip_bf16.h>

// Problem constants
#define BB 2
#define TT 2048
#define CC 768
#define HH 8
#define DD 96
#define N3 2304   // 3*C
#define BH (BB*HH)

typedef __bf16 bf16x8 __attribute__((ext_vector_type(8)));
typedef float f32x4 __attribute__((ext_vector_type(4)));

__device__ __forceinline__ ushort f2bf(float f) {
    unsigned u = __builtin_bit_cast(unsigned, f);
    u += 0x7fffu + ((u >> 16) & 1u);   // round-to-nearest-even
    return (ushort)(u >> 16);
}

// ---------------------------------------------------------------------------
// Cast fp32 -> bf16, flat (n divisible by 2048)
// ---------------------------------------------------------------------------
__global__ __launch_bounds__(256) void cast_bf16_kernel(
    const float* __restrict__ src, ushort* __restrict__ dst)
{
    const size_t i = ((size_t)blockIdx.x * 256 + threadIdx.x) * 8;
    float4 a = *(const float4*)&src[i];
    float4 b = *(const float4*)&src[i + 4];
    ushort tmp[8] = {f2bf(a.x), f2bf(a.y), f2bf(a.z), f2bf(a.w),
                     f2bf(b.x), f2bf(b.y), f2bf(b.z), f2bf(b.w)};
    *(uint4*)&dst[i] = *(const uint4*)tmp;
}

// ---------------------------------------------------------------------------
// Transpose-cast: src fp32 [R][C] -> dst bf16 [C][R].  64x64 LDS tiles.
// ---------------------------------------------------------------------------
__global__ __launch_bounds__(256) void tcast_bf16_kernel(
    const float* __restrict__ src, ushort* __restrict__ dst, int R, int C)
{
    __shared__ ushort t[64][66];
    const int tid = threadIdx.x;
    const int c0 = blockIdx.x * 64;
    const int r0 = blockIdx.y * 64;
    const int tx = tid & 63;
    const int ty = tid >> 6;     // 0..3
    #pragma unroll
    for (int i = 0; i < 16; ++i) {
        const int row = ty * 16 + i;
        t[tx][row] = f2bf(src[(size_t)(r0 + row) * C + c0 + tx]);
    }
    __syncthreads();
    #pragma unroll
    for (int i = 0; i < 16; ++i) {
        const int row = ty * 16 + i;     // = col of src tile
        dst[(size_t)(c0 + row) * R + r0 + tx] = t[row][tx];
    }
}

// ---------------------------------------------------------------------------
// Shared MFMA GEMM mainloop (m97 structure): C[128,128] tile, BK=32, K=768.
// A bf16 [M][768] row-major, Bt bf16 [N][768] row-major (i.e. B transposed).
// 4 waves in 2x2; each wave 64x64 via 4x4 grid of 16x16x32 MFMAs.
// ---------------------------------------------------------------------------
__device__ __forceinline__ void mfma_gemm_768(
    const ushort* __restrict__ A, const ushort* __restrict__ Bt,
    int m0, int n0, ushort* Al, ushort* Bl, f32x4 (&acc)[4][4])
{
    const int tid  = threadIdx.x;
    const int w    = tid >> 6;
    const int lane = tid & 63;
    const int quad = lane >> 4;
    const int col  = lane & 15;
    const int rm   = (w >> 1) * 64;
    const int cn   = (w & 1) * 64;

    // staging: chunk c = tid + i*256; row = c>>2, sub = c&3  (16B chunks)
    const int row_s = tid >> 2, sub = tid & 3;
    const ushort* ga0 = A  + (size_t)(m0 + row_s) * 768 + sub * 8;
    const ushort* gb0 = Bt + (size_t)(n0 + row_s) * 768 + sub * 8;
    ushort* la0 = Al + tid * 8;
    ushort* lb0 = Bl + tid * 8;

    for (int k0 = 0; k0 < 768; k0 += 32) {
        __syncthreads();
        __builtin_amdgcn_global_load_lds(
            (const __attribute__((address_space(1))) void*)(ga0 + k0),
            (__attribute__((address_space(3))) void*)(la0), 16, 0, 0);
        __builtin_amdgcn_global_load_lds(
            (const __attribute__((address_space(1))) void*)(ga0 + (size_t)64*768 + k0),
            (__attribute__((address_space(3))) void*)(la0 + 2048), 16, 0, 0);
        __builtin_amdgcn_global_load_lds(
            (const __attribute__((address_space(1))) void*)(gb0 + k0),
            (__attribute__((address_space(3))) void*)(lb0), 16, 0, 0);
        __builtin_amdgcn_global_load_lds(
            (const __attribute__((address_space(1))) void*)(gb0 + (size_t)64*768 + k0),
            (__attribute__((address_space(3))) void*)(lb0 + 2048), 16, 0, 0);
        __syncthreads();

        bf16x8 af[4], bfr[4];
        #pragma unroll
        for (int i = 0; i < 4; ++i)
            af[i] = *(const bf16x8*)&Al[(rm + i*16 + col) * 32 + quad * 8];
        #pragma unroll
        for (int j = 0; j < 4; ++j)
            bfr[j] = *(const bf16x8*)&Bl[(cn + j*16 + col) * 32 + quad * 8];
        #pragma unroll
        for (int i = 0; i < 4; ++i)
            #pragma unroll
            for (int j = 0; j < 4; ++j)
                acc[i][j] = __builtin_amdgcn_mfma_f32_16x16x32_bf16(
                    af[i], bfr[j], acc[i][j], 0, 0, 0);
    }
}

// ---------------------------------------------------------------------------
// Kernel: QKV GEMM (bf16 MFMA) + scatter epilogue.
// Outputs: Qb [BH,T,96] pre-scaled, Kb [BH,T,96], Vt [BH,96,T]  (all bf16)
// Column-blocks are 128-wide; part boundaries (768,1536) are multiples of 128.
// ---------------------------------------------------------------------------
__global__ __launch_bounds__(256) void qkv_mfma_kernel(
    const ushort* __restrict__ xb, const ushort* __restrict__ Wat,
    const float* __restrict__ bias,
    ushort* __restrict__ Qb, ushort* __restrict__ Kb, ushort* __restrict__ Vt)
{
    __shared__ __align__(16) ushort Al[128 * 32];
    __shared__ __align__(16) ushort Bl[128 * 32];
    __shared__ __align__(16) ushort Tl[4][16][20];   // per-wave 16x16 transpose

    const int m0 = blockIdx.y * 128;
    const int n0 = blockIdx.x * 128;
    f32x4 acc[4][4] = {};
    mfma_gemm_768(xb, Wat, m0, n0, Al, Bl, acc);

    const int tid  = threadIdx.x;
    const int w    = tid >> 6;
    const int lane = tid & 63;
    const int quad = lane >> 4;
    const int col  = lane & 15;
    const int rm   = (w >> 1) * 64;
    const int cn   = (w & 1) * 64;
    const int part = n0 / CC;                 // 0=Q, 1=K, 2=V (uniform per block)
    const float scale = 0.10206207261596575f; // 1/sqrt(96)

    if (part < 2) {
        #pragma unroll
        for (int i = 0; i < 4; ++i) {
            #pragma unroll
            for (int j = 0; j < 4; ++j) {
                const int n = n0 + cn + j*16 + col;
                const int c = n - part * CC;
                const int h = c / DD, d = c % DD;   // 16-col block never straddles a head
                const float bn = bias[n];
                #pragma unroll
                for (int r = 0; r < 4; ++r) {
                    const int m = m0 + rm + i*16 + quad*4 + r;
                    const int b = m >> 11, t = m & 2047;
                    const int bh = b * HH + h;
                    const float v = acc[i][j][r] + bn;
                    if (part == 0) Qb[((size_t)bh*TT + t)*DD + d] = f2bf(v * scale);
                    else           Kb[((size_t)bh*TT + t)*DD + d] = f2bf(v);
                }
            }
        }
    } else {
        // V: per-wave 16x16 LDS transpose so global writes are coalesced in t
        #pragma unroll
        for (int i = 0; i < 4; ++i) {
            #pragma unroll
            for (int j = 0; j < 4; ++j) {
                const int n = n0 + cn + j*16 + col;
                const float bn = bias[n];
                ushort4 tv;
                tv.x = f2bf(acc[i][j][0] + bn);
                tv.y = f2bf(acc[i][j][1] + bn);
                tv.z = f2bf(acc[i][j][2] + bn);
                tv.w = f2bf(acc[i][j][3] + bn);
                *(ushort4*)&Tl[w][col][quad * 4] = tv;   // Tl[d'][t'] per wave
                #pragma unroll
                for (int rr = 0; rr < 4; ++rr) {
                    const int c = n0 - 2*CC + cn + j*16 + quad*4 + rr;
                    const int h = c / DD, d = c % DD;
                    const int m = m0 + rm + i*16 + col;
                    const int b = m >> 11, t = m & 2047;
                    Vt[((size_t)(b*HH + h)*DD + d)*TT + t] = Tl[w][quad*4 + rr][col];
                }
            }
        }
    }
}

// ---------------------------------------------------------------------------
// Kernel: flash-style causal attention with bf16 MFMA (unchanged from R2,
// except Y output is now bf16 for the MFMA proj GEMM).
// ---------------------------------------------------------------------------
__global__ __launch_bounds__(256) void attn_mfma_kernel(
    const ushort* __restrict__ Qb, const ushort* __restrict__ Kb,
    const ushort* __restrict__ Vt, ushort* __restrict__ Yb)
{
    __shared__ __align__(16) ushort Kl[64][104];     // [key][d], +8 pad
    __shared__ __align__(16) ushort Vl[96][72];      // [d][key], +8 pad
    __shared__ __align__(16) ushort Pl[4][16][72];   // per-wave P round-trip

    const int tid  = threadIdx.x;
    const int w    = tid >> 6;
    const int lane = tid & 63;
    const int quad = lane >> 4;
    const int col  = lane & 15;
    const int qb   = blockIdx.x;
    const int bh   = blockIdx.y;
    const int q0   = qb * 64;

    const int qrow = q0 + w*16 + col;
    const ushort* Qp = Qb + ((size_t)bh*TT + qrow)*DD;
    bf16x8 qf[3];
    #pragma unroll
    for (int ks = 0; ks < 3; ++ks)
        qf[ks] = *(const bf16x8*)(Qp + ks*32 + quad*8);

    const ushort* Kg = Kb + (size_t)bh*TT*DD;
    const ushort* Vg = Vt + (size_t)bh*DD*TT;

    f32x4 O[6] = {};
    float mrow[4], lrow[4];
    #pragma unroll
    for (int r = 0; r < 4; ++r) { mrow[r] = -1e30f; lrow[r] = 0.f; }

    for (int kt = 0; kt <= qb; ++kt) {
        const int k0 = kt * 64;
        __syncthreads();
        #pragma unroll
        for (int i = 0; i < 3; ++i) {
            int l = tid + i*256;
            int row = l / 12, ch = l % 12;
            uint4 vv = *(const uint4*)(Kg + (size_t)(k0 + row)*DD + ch*8);
            *(uint4*)&Kl[row][ch*8] = vv;
        }
        #pragma unroll
        for (int i = 0; i < 3; ++i) {
            int l = tid + i*256;
            int row = l / 8, ch = l % 8;
            uint4 vv = *(const uint4*)(Vg + (size_t)row*TT + k0 + ch*8);
            *(uint4*)&Vl[row][ch*8] = vv;
        }
        __syncthreads();

        f32x4 s[4];
        #pragma unroll
        for (int c = 0; c < 4; ++c) {
            f32x4 a = {0.f, 0.f, 0.f, 0.f};
            #pragma unroll
            for (int ks = 0; ks < 3; ++ks) {
                bf16x8 bf = *(const bf16x8*)&Kl[c*16 + col][ks*32 + quad*8];
                a = __builtin_amdgcn_mfma_f32_16x16x32_bf16(qf[ks], bf, a, 0, 0, 0);
            }
            s[c] = a;
        }

        if (kt == qb) {
            #pragma unroll
            for (int c = 0; c < 4; ++c)
                #pragma unroll
                for (int r = 0; r < 4; ++r) {
                    const int qlb = w*16 + quad*4 + r;
                    const int klb = c*16 + col;
                    if (klb > qlb) s[c][r] = -1e30f;
                }
        }

        float ps[4][4];
        #pragma unroll
        for (int r = 0; r < 4; ++r) {
            float mx = fmaxf(fmaxf(s[0][r], s[1][r]), fmaxf(s[2][r], s[3][r]));
            mx = fmaxf(mx, __shfl_xor(mx, 1, 64));
            mx = fmaxf(mx, __shfl_xor(mx, 2, 64));
            mx = fmaxf(mx, __shfl_xor(mx, 4, 64));
            mx = fmaxf(mx, __shfl_xor(mx, 8, 64));
            const float mnew  = fmaxf(mrow[r], mx);
            const float alpha = __expf(mrow[r] - mnew);
            mrow[r] = mnew;
            float rs = 0.f;
            #pragma unroll
            for (int c = 0; c < 4; ++c) {
                const float p = __expf(s[c][r] - mnew);
                ps[c][r] = p;
                rs += p;
            }
            rs += __shfl_xor(rs, 1, 64);
            rs += __shfl_xor(rs, 2, 64);
            rs += __shfl_xor(rs, 4, 64);
            rs += __shfl_xor(rs, 8, 64);
            lrow[r] = lrow[r]*alpha + rs;
            #pragma unroll
            for (int c2 = 0; c2 < 6; ++c2)
                O[c2][r] *= alpha;
        }

        #pragma unroll
        for (int c = 0; c < 4; ++c)
            #pragma unroll
            for (int r = 0; r < 4; ++r)
                Pl[w][quad*4 + r][c*16 + col] = f2bf(ps[c][r]);

        bf16x8 pf0 = *(const bf16x8*)&Pl[w][col][quad*8];
        bf16x8 pf1 = *(const bf16x8*)&Pl[w][col][32 + quad*8];

        #pragma unroll
        for (int c2 = 0; c2 < 6; ++c2) {
            bf16x8 vb0 = *(const bf16x8*)&Vl[c2*16 + col][quad*8];
            bf16x8 vb1 = *(const bf16x8*)&Vl[c2*16 + col][32 + quad*8];
            O[c2] = __builtin_amdgcn_mfma_f32_16x16x32_bf16(pf0, vb0, O[c2], 0, 0, 0);
            O[c2] = __builtin_amdgcn_mfma_f32_16x16x32_bf16(pf1, vb1, O[c2], 0, 0, 0);
        }
    }

    const int b = bh >> 3, h = bh & 7;
    #pragma unroll
    for (int r = 0; r < 4; ++r) {
        const int q = q0 + w*16 + quad*4 + r;
        const float inv = 1.0f / lrow[r];
        ushort* Yp = Yb + ((size_t)b*TT + q)*CC + h*DD;
        #pragma unroll
        for (int c2 = 0; c2 < 6; ++c2)
            Yp[c2*16 + col] = f2bf(O[c2][r] * inv);
    }
}

// ---------------------------------------------------------------------------
// Kernel: proj GEMM (bf16 MFMA), out = Yb @ W_proj + b_proj, fp32 out.
// ---------------------------------------------------------------------------
__global__ __launch_bounds__(256) void proj_mfma_kernel(
    const ushort* __restrict__ Yb, const ushort* __restrict__ Wpt,
    const float* __restrict__ bias, float* __restrict__ out)
{
    __shared__ __align__(16) ushort Al[128 * 32];
    __shared__ __align__(16) ushort Bl[128 * 32];

    const int m0 = blockIdx.y * 128;
    const int n0 = blockIdx.x * 128;
    f32x4 acc[4][4] = {};
    mfma_gemm_768(Yb, Wpt, m0, n0, Al, Bl, acc);

    const int tid  = threadIdx.x;
    const int w    = tid >> 6;
    const int lane = tid & 63;
    const int quad = lane >> 4;
    const int col  = lane & 15;
    const int rm   = (w >> 1) * 64;
    const int cn   = (w & 1) * 64;

    #pragma unroll
    for (int i = 0; i < 4; ++i) {
        #pragma unroll
        for (int j = 0; j < 4; ++j) {
            const int n = n0 + cn + j*16 + col;
            const float bn = bias[n];
            #pragma unroll
            for (int r = 0; r < 4; ++r) {
                const int m = m0 + rm + i*16 + quad*4 + r;
                out[(size_t)m*CC + n] = acc[i][j][r] + bn;
            }
        }
    }
}

extern "C" void kernel_launch(void* const* d_in, const int* in_sizes, int n_in,
                              void* d_out, int out_size, void* d_ws, size_t ws_size,
                              hipStream_t stream) {
    const float* x      = (const float*)d_in[0];   // [2,2048,768]
    const float* W_attn = (const float*)d_in[1];   // [768,2304]
    const float* b_attn = (const float*)d_in[2];   // [2304]
    const float* W_proj = (const float*)d_in[3];   // [768,768]
    const float* b_proj = (const float*)d_in[4];   // [768]
    float* out = (float*)d_out;                    // [2,2048,768]

    const size_t SLICE = (size_t)BH * TT * DD;     // 3,145,728
    ushort* xb  = (ushort*)d_ws;                   // bf16 [4096,768]
    ushort* Qb  = xb  + SLICE;                     // bf16 [BH,T,96] pre-scaled
    ushort* Kb  = Qb  + SLICE;                     // bf16 [BH,T,96]
    ushort* Vt  = Kb  + SLICE;                     // bf16 [BH,96,T]
    ushort* Yb  = Vt  + SLICE;                     // bf16 [4096,768]
    ushort* Wat = Yb  + SLICE;                     // bf16 [2304,768] (W_attn^T)
    ushort* Wpt = Wat + (size_t)N3 * CC;           // bf16 [768,768]  (W_proj^T)

    cast_bf16_kernel<<<dim3(SLICE / (256*8)), 256, 0, stream>>>(x, xb);
    tcast_bf16_kernel<<<dim3(N3/64, CC/64), 256, 0, stream>>>(W_attn, Wat, CC, N3);
    tcast_bf16_kernel<<<dim3(CC/64, CC/64), 256, 0, stream>>>(W_proj, Wpt, CC, CC);
    qkv_mfma_kernel<<<dim3(N3/128, (BB*TT)/128), 256, 0, stream>>>(
        xb, Wat, b_attn, Qb, Kb, Vt);
    attn_mfma_kernel<<<dim3(TT/64, BH), 256, 0, stream>>>(Qb, Kb, Vt, Yb);
    proj_mfma_kernel<<<dim3(CC/128, (BB*TT)/128), 256, 0, stream>>>(
        Yb, Wpt, b_proj, out);
}

// Round 4
// 192.688 us; speedup vs baseline: 10.6126x; 1.1305x over previous
//
#include <hip/hip_runtime.h>
#include <hip/hip_bf16.h>

// Problem constants
#define BB 2
#define TT 2048
#define CC 768
#define HH 8
#define DD 96
#define N3 2304   // 3*C
#define BH (BB*HH)

typedef __bf16 bf16x8 __attribute__((ext_vector_type(8)));
typedef float f32x4 __attribute__((ext_vector_type(4)));

__device__ __forceinline__ ushort f2bf(float f) {
    unsigned u = __builtin_bit_cast(unsigned, f);
    u += 0x7fffu + ((u >> 16) & 1u);   // round-to-nearest-even
    return (ushort)(u >> 16);
}
__device__ __forceinline__ float bf2f(ushort u) {
    return __builtin_bit_cast(float, (unsigned)u << 16);
}

// ---------------------------------------------------------------------------
// Cast fp32 -> bf16, flat
// ---------------------------------------------------------------------------
__global__ __launch_bounds__(256) void cast_bf16_kernel(
    const float* __restrict__ src, ushort* __restrict__ dst)
{
    const size_t i = ((size_t)blockIdx.x * 256 + threadIdx.x) * 8;
    float4 a = *(const float4*)&src[i];
    float4 b = *(const float4*)&src[i + 4];
    ushort tmp[8] = {f2bf(a.x), f2bf(a.y), f2bf(a.z), f2bf(a.w),
                     f2bf(b.x), f2bf(b.y), f2bf(b.z), f2bf(b.w)};
    *(uint4*)&dst[i] = *(const uint4*)tmp;
}

// ---------------------------------------------------------------------------
// Transpose-cast: src fp32 [R][C] -> dst bf16 [C][R].  64x64 LDS tiles.
// ---------------------------------------------------------------------------
__global__ __launch_bounds__(256) void tcast_bf16_kernel(
    const float* __restrict__ src, ushort* __restrict__ dst, int R, int C)
{
    __shared__ ushort t[64][66];
    const int tid = threadIdx.x;
    const int c0 = blockIdx.x * 64;
    const int r0 = blockIdx.y * 64;
    const int tx = tid & 63;
    const int ty = tid >> 6;
    #pragma unroll
    for (int i = 0; i < 16; ++i) {
        const int row = ty * 16 + i;
        t[tx][row] = f2bf(src[(size_t)(r0 + row) * C + c0 + tx]);
    }
    __syncthreads();
    #pragma unroll
    for (int i = 0; i < 16; ++i) {
        const int row = ty * 16 + i;
        dst[(size_t)(c0 + row) * R + r0 + tx] = t[row][tx];
    }
}

// ---------------------------------------------------------------------------
// Shared MFMA GEMM mainloop (m97 structure): C[128,128] tile, BK=32, K=768.
// ---------------------------------------------------------------------------
__device__ __forceinline__ void mfma_gemm_768(
    const ushort* __restrict__ A, const ushort* __restrict__ Bt,
    int m0, int n0, ushort* Al, ushort* Bl, f32x4 (&acc)[4][4])
{
    const int tid  = threadIdx.x;
    const int w    = tid >> 6;
    const int lane = tid & 63;
    const int quad = lane >> 4;
    const int col  = lane & 15;
    const int rm   = (w >> 1) * 64;
    const int cn   = (w & 1) * 64;

    const int row_s = tid >> 2, sub = tid & 3;
    const ushort* ga0 = A  + (size_t)(m0 + row_s) * 768 + sub * 8;
    const ushort* gb0 = Bt + (size_t)(n0 + row_s) * 768 + sub * 8;
    ushort* la0 = Al + tid * 8;
    ushort* lb0 = Bl + tid * 8;

    for (int k0 = 0; k0 < 768; k0 += 32) {
        __syncthreads();
        __builtin_amdgcn_global_load_lds(
            (const __attribute__((address_space(1))) void*)(ga0 + k0),
            (__attribute__((address_space(3))) void*)(la0), 16, 0, 0);
        __builtin_amdgcn_global_load_lds(
            (const __attribute__((address_space(1))) void*)(ga0 + (size_t)64*768 + k0),
            (__attribute__((address_space(3))) void*)(la0 + 2048), 16, 0, 0);
        __builtin_amdgcn_global_load_lds(
            (const __attribute__((address_space(1))) void*)(gb0 + k0),
            (__attribute__((address_space(3))) void*)(lb0), 16, 0, 0);
        __builtin_amdgcn_global_load_lds(
            (const __attribute__((address_space(1))) void*)(gb0 + (size_t)64*768 + k0),
            (__attribute__((address_space(3))) void*)(lb0 + 2048), 16, 0, 0);
        __syncthreads();

        bf16x8 af[4], bfr[4];
        #pragma unroll
        for (int i = 0; i < 4; ++i)
            af[i] = *(const bf16x8*)&Al[(rm + i*16 + col) * 32 + quad * 8];
        #pragma unroll
        for (int j = 0; j < 4; ++j)
            bfr[j] = *(const bf16x8*)&Bl[(cn + j*16 + col) * 32 + quad * 8];
        #pragma unroll
        for (int i = 0; i < 4; ++i)
            #pragma unroll
            for (int j = 0; j < 4; ++j)
                acc[i][j] = __builtin_amdgcn_mfma_f32_16x16x32_bf16(
                    af[i], bfr[j], acc[i][j], 0, 0, 0);
    }
}

// ---------------------------------------------------------------------------
// Kernel: QKV GEMM (bf16 MFMA) + scatter epilogue.
// ---------------------------------------------------------------------------
__global__ __launch_bounds__(256) void qkv_mfma_kernel(
    const ushort* __restrict__ xb, const ushort* __restrict__ Wat,
    const float* __restrict__ bias,
    ushort* __restrict__ Qb, ushort* __restrict__ Kb, ushort* __restrict__ Vt)
{
    __shared__ __align__(16) ushort Al[128 * 32];
    __shared__ __align__(16) ushort Bl[128 * 32];
    __shared__ __align__(16) ushort Tl[4][16][20];

    const int m0 = blockIdx.y * 128;
    const int n0 = blockIdx.x * 128;
    f32x4 acc[4][4] = {};
    mfma_gemm_768(xb, Wat, m0, n0, Al, Bl, acc);

    const int tid  = threadIdx.x;
    const int w    = tid >> 6;
    const int lane = tid & 63;
    const int quad = lane >> 4;
    const int col  = lane & 15;
    const int rm   = (w >> 1) * 64;
    const int cn   = (w & 1) * 64;
    const int part = n0 / CC;
    const float scale = 0.10206207261596575f;

    if (part < 2) {
        #pragma unroll
        for (int i = 0; i < 4; ++i) {
            #pragma unroll
            for (int j = 0; j < 4; ++j) {
                const int n = n0 + cn + j*16 + col;
                const int c = n - part * CC;
                const int h = c / DD, d = c % DD;
                const float bn = bias[n];
                #pragma unroll
                for (int r = 0; r < 4; ++r) {
                    const int m = m0 + rm + i*16 + quad*4 + r;
                    const int b = m >> 11, t = m & 2047;
                    const int bh = b * HH + h;
                    const float v = acc[i][j][r] + bn;
                    if (part == 0) Qb[((size_t)bh*TT + t)*DD + d] = f2bf(v * scale);
                    else           Kb[((size_t)bh*TT + t)*DD + d] = f2bf(v);
                }
            }
        }
    } else {
        #pragma unroll
        for (int i = 0; i < 4; ++i) {
            #pragma unroll
            for (int j = 0; j < 4; ++j) {
                const int n = n0 + cn + j*16 + col;
                const float bn = bias[n];
                ushort4 tv;
                tv.x = f2bf(acc[i][j][0] + bn);
                tv.y = f2bf(acc[i][j][1] + bn);
                tv.z = f2bf(acc[i][j][2] + bn);
                tv.w = f2bf(acc[i][j][3] + bn);
                *(ushort4*)&Tl[w][col][quad * 4] = tv;
                #pragma unroll
                for (int rr = 0; rr < 4; ++rr) {
                    const int c = n0 - 2*CC + cn + j*16 + quad*4 + rr;
                    const int h = c / DD, d = c % DD;
                    const int m = m0 + rm + i*16 + col;
                    const int b = m >> 11, t = m & 2047;
                    Vt[((size_t)(b*HH + h)*DD + d)*TT + t] = Tl[w][quad*4 + rr][col];
                }
            }
        }
    }
}

// ---------------------------------------------------------------------------
// Kernel: flash attention, split-K (flash-decoding) partials.
// Work item = (bh, qb, chunk of <=8 key-tiles). 80 items per bh, 1280 total.
// Writes unnormalized partial O (bf16) + m,l (fp32) per item.
// l is accumulated via a ones-column in V (d=96) -> O[6], no sum-shuffles.
// ---------------------------------------------------------------------------
__global__ __launch_bounds__(256) void attn_mfma_kernel(
    const ushort* __restrict__ Qb, const ushort* __restrict__ Kb,
    const ushort* __restrict__ Vt, ushort* __restrict__ Opart,
    float* __restrict__ Mpart, float* __restrict__ Lpart)
{
    __shared__ __align__(16) ushort Kl[64][104];     // [key][d], +8 pad
    __shared__ __align__(16) ushort Vl[112][72];     // [d][key]; row 96 = ones
    __shared__ __align__(16) ushort Pl[4][16][72];   // per-wave P round-trip

    const int it  = blockIdx.x;       // 0..1279
    const int bh  = it / 80;
    const int rem = it % 80;
    int qb, ci;
    if (rem < 8)       { qb = rem;               ci = 0; }
    else if (rem < 24) { int t = rem - 8;  qb = 8  + t/2; ci = t % 2; }
    else if (rem < 48) { int t = rem - 24; qb = 16 + t/3; ci = t % 3; }
    else               { int t = rem - 48; qb = 24 + t/4; ci = t % 4; }

    const int tid  = threadIdx.x;
    const int w    = tid >> 6;
    const int lane = tid & 63;
    const int quad = lane >> 4;
    const int col  = lane & 15;
    const int q0   = qb * 64;

    const int qrow = q0 + w*16 + col;
    const ushort* Qp = Qb + ((size_t)bh*TT + qrow)*DD;
    bf16x8 qf[3];
    #pragma unroll
    for (int ks = 0; ks < 3; ++ks)
        qf[ks] = *(const bf16x8*)(Qp + ks*32 + quad*8);

    const ushort* Kg = Kb + (size_t)bh*TT*DD;
    const ushort* Vg = Vt + (size_t)bh*DD*TT;

    if (tid < 64) Vl[96][tid] = 0x3F80;   // bf16 1.0 ones-column

    f32x4 O[7] = {};                      // O[6] accumulates l
    float mrow[4];
    #pragma unroll
    for (int r = 0; r < 4; ++r) mrow[r] = -1e30f;

    const int kts = ci * 8;
    const int kte = min(kts + 8, qb + 1);

    for (int kt = kts; kt < kte; ++kt) {
        const int k0 = kt * 64;
        __syncthreads();
        #pragma unroll
        for (int i = 0; i < 3; ++i) {
            int l = tid + i*256;
            int row = l / 12, ch = l % 12;
            uint4 vv = *(const uint4*)(Kg + (size_t)(k0 + row)*DD + ch*8);
            *(uint4*)&Kl[row][ch*8] = vv;
        }
        #pragma unroll
        for (int i = 0; i < 3; ++i) {
            int l = tid + i*256;
            int row = l / 8, ch = l % 8;
            uint4 vv = *(const uint4*)(Vg + (size_t)row*TT + k0 + ch*8);
            *(uint4*)&Vl[row][ch*8] = vv;
        }
        __syncthreads();

        f32x4 s[4];
        #pragma unroll
        for (int c = 0; c < 4; ++c) {
            f32x4 a = {0.f, 0.f, 0.f, 0.f};
            #pragma unroll
            for (int ks = 0; ks < 3; ++ks) {
                bf16x8 bf = *(const bf16x8*)&Kl[c*16 + col][ks*32 + quad*8];
                a = __builtin_amdgcn_mfma_f32_16x16x32_bf16(qf[ks], bf, a, 0, 0, 0);
            }
            s[c] = a;
        }

        if (kt == qb) {
            #pragma unroll
            for (int c = 0; c < 4; ++c)
                #pragma unroll
                for (int r = 0; r < 4; ++r) {
                    const int qlb = w*16 + quad*4 + r;
                    const int klb = c*16 + col;
                    if (klb > qlb) s[c][r] = -1e30f;
                }
        }

        float ps[4][4];
        #pragma unroll
        for (int r = 0; r < 4; ++r) {
            float mx = fmaxf(fmaxf(s[0][r], s[1][r]), fmaxf(s[2][r], s[3][r]));
            mx = fmaxf(mx, __shfl_xor(mx, 1, 64));
            mx = fmaxf(mx, __shfl_xor(mx, 2, 64));
            mx = fmaxf(mx, __shfl_xor(mx, 4, 64));
            mx = fmaxf(mx, __shfl_xor(mx, 8, 64));
            const float mnew  = fmaxf(mrow[r], mx);
            const float alpha = __expf(mrow[r] - mnew);
            mrow[r] = mnew;
            #pragma unroll
            for (int c = 0; c < 4; ++c)
                ps[c][r] = __expf(s[c][r] - mnew);
            #pragma unroll
            for (int c2 = 0; c2 < 7; ++c2)
                O[c2][r] *= alpha;
        }

        #pragma unroll
        for (int c = 0; c < 4; ++c)
            #pragma unroll
            for (int r = 0; r < 4; ++r)
                Pl[w][quad*4 + r][c*16 + col] = f2bf(ps[c][r]);

        bf16x8 pf0 = *(const bf16x8*)&Pl[w][col][quad*8];
        bf16x8 pf1 = *(const bf16x8*)&Pl[w][col][32 + quad*8];

        #pragma unroll
        for (int c2 = 0; c2 < 7; ++c2) {
            bf16x8 vb0 = *(const bf16x8*)&Vl[c2*16 + col][quad*8];
            bf16x8 vb1 = *(const bf16x8*)&Vl[c2*16 + col][32 + quad*8];
            O[c2] = __builtin_amdgcn_mfma_f32_16x16x32_bf16(pf0, vb0, O[c2], 0, 0, 0);
            O[c2] = __builtin_amdgcn_mfma_f32_16x16x32_bf16(pf1, vb1, O[c2], 0, 0, 0);
        }
    }

    // ---- write partial: O (bf16), m, l (fp32, col==0 lanes hold true l) ----
    const size_t slot = (size_t)it;
    #pragma unroll
    for (int r = 0; r < 4; ++r) {
        const int rl = w*16 + quad*4 + r;
        ushort* Op = Opart + (slot*64 + rl)*DD;
        #pragma unroll
        for (int c2 = 0; c2 < 6; ++c2)
            Op[c2*16 + col] = f2bf(O[c2][r]);
    }
    if (col == 0) {
        #pragma unroll
        for (int r = 0; r < 4; ++r) {
            const int rl = w*16 + quad*4 + r;
            Mpart[slot*64 + rl] = mrow[r];
            Lpart[slot*64 + rl] = O[6][r];
        }
    }
}

// ---------------------------------------------------------------------------
// Kernel: combine split-K partials -> Yb (bf16).
// Grid (32, 16): block = (qb, bh); 256 threads: row = tid>>2, 24 cols each.
// ---------------------------------------------------------------------------
__global__ __launch_bounds__(256) void attn_combine_kernel(
    const ushort* __restrict__ Opart, const float* __restrict__ Mpart,
    const float* __restrict__ Lpart, ushort* __restrict__ Yb)
{
    const int qb = blockIdx.x;
    const int bh = blockIdx.y;
    const int nC = (qb >> 3) + 1;
    int bse;
    if (qb < 8)       bse = qb;
    else if (qb < 16) bse = 8  + 2*(qb - 8);
    else if (qb < 24) bse = 24 + 3*(qb - 16);
    else              bse = 48 + 4*(qb - 24);
    const int item0 = bh * 80 + bse;

    const int tid = threadIdx.x;
    const int row = tid >> 2;
    const int jj  = tid & 3;

    float m[4], f[4];
    float M = -1e30f;
    for (int c = 0; c < nC; ++c) {
        m[c] = Mpart[(size_t)(item0 + c)*64 + row];
        M = fmaxf(M, m[c]);
    }
    float L = 0.f;
    for (int c = 0; c < nC; ++c) {
        f[c] = __expf(m[c] - M);
        L += Lpart[(size_t)(item0 + c)*64 + row] * f[c];
    }
    const float invL = 1.0f / L;

    float acc[24] = {};
    for (int c = 0; c < nC; ++c) {
        const ushort* Op = Opart + ((size_t)(item0 + c)*64 + row)*DD + jj*24;
        const float fc = f[c];
        #pragma unroll
        for (int v = 0; v < 3; ++v) {
            uint4 pk = *(const uint4*)(Op + v*8);
            const ushort* us = (const ushort*)&pk;
            #pragma unroll
            for (int e = 0; e < 8; ++e)
                acc[v*8 + e] += fc * bf2f(us[e]);
        }
    }

    const int q = qb*64 + row;
    const int b = bh >> 3, h = bh & 7;
    ushort outv[24];
    #pragma unroll
    for (int e = 0; e < 24; ++e) outv[e] = f2bf(acc[e] * invL);
    ushort* Yp = Yb + ((size_t)b*TT + q)*CC + h*DD + jj*24;
    #pragma unroll
    for (int v = 0; v < 3; ++v)
        *(uint4*)(Yp + v*8) = *(const uint4*)&outv[v*8];
}

// ---------------------------------------------------------------------------
// Kernel: proj GEMM (bf16 MFMA), out = Yb @ W_proj + b_proj, fp32 out.
// ---------------------------------------------------------------------------
__global__ __launch_bounds__(256) void proj_mfma_kernel(
    const ushort* __restrict__ Yb, const ushort* __restrict__ Wpt,
    const float* __restrict__ bias, float* __restrict__ out)
{
    __shared__ __align__(16) ushort Al[128 * 32];
    __shared__ __align__(16) ushort Bl[128 * 32];

    const int m0 = blockIdx.y * 128;
    const int n0 = blockIdx.x * 128;
    f32x4 acc[4][4] = {};
    mfma_gemm_768(Yb, Wpt, m0, n0, Al, Bl, acc);

    const int tid  = threadIdx.x;
    const int w    = tid >> 6;
    const int lane = tid & 63;
    const int quad = lane >> 4;
    const int col  = lane & 15;
    const int rm   = (w >> 1) * 64;
    const int cn   = (w & 1) * 64;

    #pragma unroll
    for (int i = 0; i < 4; ++i) {
        #pragma unroll
        for (int j = 0; j < 4; ++j) {
            const int n = n0 + cn + j*16 + col;
            const float bn = bias[n];
            #pragma unroll
            for (int r = 0; r < 4; ++r) {
                const int m = m0 + rm + i*16 + quad*4 + r;
                out[(size_t)m*CC + n] = acc[i][j][r] + bn;
            }
        }
    }
}

extern "C" void kernel_launch(void* const* d_in, const int* in_sizes, int n_in,
                              void* d_out, int out_size, void* d_ws, size_t ws_size,
                              hipStream_t stream) {
    const float* x      = (const float*)d_in[0];
    const float* W_attn = (const float*)d_in[1];
    const float* b_attn = (const float*)d_in[2];
    const float* W_proj = (const float*)d_in[3];
    const float* b_proj = (const float*)d_in[4];
    float* out = (float*)d_out;

    const size_t SLICE   = (size_t)BH * TT * DD;   // 3,145,728
    const size_t OPART_E = (size_t)1280 * 64 * DD; // 7,864,320 bf16
    ushort* Opart = (ushort*)d_ws;                 // [1280][64][96] bf16
    ushort* xb    = Opart;                         // aliases Opart (xb dead before attn)
    ushort* Qb    = Opart + OPART_E;
    ushort* Kb    = Qb  + SLICE;
    ushort* Vt    = Kb  + SLICE;
    ushort* Yb    = Vt  + SLICE;
    ushort* Wat   = Yb  + SLICE;                   // [2304][768]
    ushort* Wpt   = Wat + (size_t)N3 * CC;         // [768][768]
    float*  Mpart = (float*)(Wpt + (size_t)CC * CC);  // [1280][64]
    float*  Lpart = Mpart + (size_t)1280 * 64;

    cast_bf16_kernel<<<dim3(SLICE / (256*8)), 256, 0, stream>>>(x, xb);
    tcast_bf16_kernel<<<dim3(N3/64, CC/64), 256, 0, stream>>>(W_attn, Wat, CC, N3);
    tcast_bf16_kernel<<<dim3(CC/64, CC/64), 256, 0, stream>>>(W_proj, Wpt, CC, CC);
    qkv_mfma_kernel<<<dim3(N3/128, (BB*TT)/128), 256, 0, stream>>>(
        xb, Wat, b_attn, Qb, Kb, Vt);
    attn_mfma_kernel<<<dim3(1280), 256, 0, stream>>>(
        Qb, Kb, Vt, Opart, Mpart, Lpart);
    attn_combine_kernel<<<dim3(32, BH), 256, 0, stream>>>(
        Opart, Mpart, Lpart, Yb);
    proj_mfma_kernel<<<dim3(CC/128, (BB*TT)/128), 256, 0, stream>>>(
        Yb, Wpt, b_proj, out);
}